// Round 8
// baseline (215.735 us; speedup 1.0000x reference)
//
#include <hip/hip_runtime.h>
#include <hip/hip_bf16.h>

// N=8192 rows, BD=64 code dim, CD=512 channel dim
#define NN 8192
#define BD 64
#define CDIM 512

typedef __attribute__((ext_vector_type(4))) float f32x4;
typedef __attribute__((ext_vector_type(4))) unsigned int u32x4;
typedef __attribute__((ext_vector_type(8))) __bf16 bf16x8;

// Fragment-major layouts (elems = unsigned short), frag = 512 ushorts = 1 KB:
//  adjF frag(it,kt): it=i/16 [0,512), kt=k/32 [0,256): off=(it*256+kt)*512+lane*8
//    lane=q*16+m holds adj[it*16+m][kt*32+q*8 .. +7]   (A-operand layout)
//  fcF  frag(nt,kt): nt=n/16 [0,32), kt=k/32 [0,256):  off=(nt*256+kt)*512+lane*8
//    lane holds fc2[kt*32+q*8 .. +7][nt*16+m]          (B-operand layout)
//  cbnF frag(it,ct): off=(it*16+ct)*512+lane*8  (A) ;  WF frag(nt,ct): off=(nt*16+ct)*512+lane*8 (B)

static __device__ __forceinline__ unsigned short f2bf(float x) {
    unsigned int u = __float_as_uint(x);
    u += 0x7fffu + ((u >> 16) & 1u);   // RTNE
    return (unsigned short)(u >> 16);
}

static __device__ __forceinline__ f32x4 mfma16(u32x4 a, u32x4 b, f32x4 c) {
    return __builtin_amdgcn_mfma_f32_16x16x32_bf16(
        __builtin_bit_cast(bf16x8, a), __builtin_bit_cast(bf16x8, b), c, 0, 0, 0);
}

static __device__ __forceinline__ u32x4 cvt8(const float* __restrict__ p) {
    float4 a = *(const float4*)p;
    float4 b = *(const float4*)(p + 4);
    u32x4 r;
    r.x = (unsigned)f2bf(a.x) | ((unsigned)f2bf(a.y) << 16);
    r.y = (unsigned)f2bf(a.z) | ((unsigned)f2bf(a.w) << 16);
    r.z = (unsigned)f2bf(b.x) | ((unsigned)f2bf(b.y) << 16);
    r.w = (unsigned)f2bf(b.z) | ((unsigned)f2bf(b.w) << 16);
    return r;
}

// adj = (max(1 - |2*dot - si - sj|/64, 0))^1.4
static __device__ __forceinline__ float adj_fn(float dot, float sij) {
    float x = fabsf(fmaf(2.0f, dot, -sij));
    float base = fmaxf(fmaf(-0.015625f, x, 1.0f), 0.0f);
    return exp2f(1.4f * __log2f(base));   // pow(0,1.4)=0 via -inf
}

// ---------------- prep: bbn -> bf16 (row-major), row sums s ----------------
__global__ void prep_kernel(const float* __restrict__ bbn,
                            unsigned short* __restrict__ tbf,
                            float* __restrict__ s) {
    int gid = blockIdx.x * blockDim.x + threadIdx.x;  // 16 threads/row
    int row = gid >> 4;
    int part = gid & 15;
    float4 v = *(const float4*)(bbn + row * BD + part * 4);
    ushort4 o;
    o.x = f2bf(v.x); o.y = f2bf(v.y); o.z = f2bf(v.z); o.w = f2bf(v.w);
    *(ushort4*)(tbf + row * BD + part * 4) = o;
    float ps = v.x + v.y + v.z + v.w;
    ps += __shfl_xor(ps, 1); ps += __shfl_xor(ps, 2);
    ps += __shfl_xor(ps, 4); ps += __shfl_xor(ps, 8);
    if (part == 0) s[row] = ps;
}

// ---------------- prep_cw: cbn -> A-frag bf16, W -> B-frag bf16 ----------------
__global__ __launch_bounds__(256) void prep_cw_kernel(const float* __restrict__ cbn,
                                                      const float* __restrict__ W,
                                                      unsigned short* __restrict__ cbnF,
                                                      unsigned short* __restrict__ WF) {
    const int lane = threadIdx.x & 63;
    const int wave = threadIdx.x >> 6;
    const int m = lane & 15, q = lane >> 4;
    if (blockIdx.x < 512) {
#pragma unroll
        for (int t = 0; t < 4; ++t) {
            int f = blockIdx.x * 16 + wave * 4 + t;   // 8192 frags
            int it = f >> 4, ct = f & 15;
            u32x4 v = cvt8(cbn + (size_t)(it * 16 + m) * CDIM + ct * 32 + q * 8);
            *(u32x4*)(cbnF + (size_t)f * 512 + lane * 8) = v;
        }
    } else {
#pragma unroll
        for (int t = 0; t < 4; ++t) {
            int f = (blockIdx.x - 512) * 16 + wave * 4 + t;   // 512 frags
            int nt = f >> 4, ct = f & 15;
            u32x4 v = cvt8(W + (size_t)(nt * 16 + m) * CDIM + ct * 32 + q * 8);
            *(u32x4*)(WF + (size_t)f * 512 + lane * 8) = v;
        }
    }
}

// ---------------- scoredeg: adjF = frag-major bf16 adj, d[i] = row sums ----------------
// grid (128 i-tiles, 16 j-chunks of 512) -> 8 blocks/CU. Each wave owns a 32-j strip per
// iter = one kt for all 4 it-frags -> transpose is WAVE-PRIVATE (no __syncthreads at all).
__global__ __launch_bounds__(256) void scoredeg_kernel(const unsigned short* __restrict__ tbf,
                                                       const float* __restrict__ s,
                                                       float* __restrict__ d,
                                                       unsigned short* __restrict__ adjF) {
    const int lane = threadIdx.x & 63;
    const int wave = threadIdx.x >> 6;   // 0..3
    const int m = lane & 15, q = lane >> 4;
    const int i0 = blockIdx.x * 64;
    const int jbase = blockIdx.y * 512;

    // per-wave private transpose strip: [32 rows][32 j + pad8] (10 KB total)
    __shared__ __align__(16) unsigned short T[4][32][40];

    u32x4 afr[4][2];
    float si[4][4];
#pragma unroll
    for (int mt = 0; mt < 4; ++mt) {
#pragma unroll
        for (int ks = 0; ks < 2; ++ks)
            afr[mt][ks] = *(const u32x4*)(tbf + (i0 + mt * 16 + m) * BD + ks * 32 + q * 8);
#pragma unroll
        for (int r = 0; r < 4; ++r) si[mt][r] = s[i0 + mt * 16 + q * 4 + r];
    }
    float dsum[4][4] = {};

    for (int iter = 0; iter < 4; ++iter) {
        const int jw = jbase + iter * 128 + wave * 32;   // this wave's 32-j strip
        u32x4 b[2][2];
        float sj[2];
#pragma unroll
        for (int jh = 0; jh < 2; ++jh) {
            b[jh][0] = *(const u32x4*)(tbf + (jw + jh * 16 + m) * BD + q * 8);
            b[jh][1] = *(const u32x4*)(tbf + (jw + jh * 16 + m) * BD + 32 + q * 8);
            sj[jh] = s[jw + jh * 16 + m];
        }
        f32x4 c[4][2];
#pragma unroll
        for (int mt = 0; mt < 4; ++mt)
#pragma unroll
            for (int jh = 0; jh < 2; ++jh) {
                f32x4 t = {0.f, 0.f, 0.f, 0.f};
                t = mfma16(afr[mt][0], b[jh][0], t);
                t = mfma16(afr[mt][1], b[jh][1], t);
                c[mt][jh] = t;
            }
        const int kt = jw >> 5;
        // two half-passes (it-pairs) through the 32-row strip: write C-layout, read A-layout
#pragma unroll
        for (int half = 0; half < 2; ++half) {
#pragma unroll
            for (int mt2 = 0; mt2 < 2; ++mt2) {
                const int mt = half * 2 + mt2;
#pragma unroll
                for (int jh = 0; jh < 2; ++jh)
#pragma unroll
                    for (int r = 0; r < 4; ++r) {
                        float a = adj_fn(c[mt][jh][r], si[mt][r] + sj[jh]);
                        dsum[mt][r] += a;
                        T[wave][mt2 * 16 + q * 4 + r][jh * 16 + m] = f2bf(a);
                    }
            }
#pragma unroll
            for (int mt2 = 0; mt2 < 2; ++mt2) {
                const int it = half * 2 + mt2;
                u32x4 v = *(const u32x4*)&T[wave][mt2 * 16 + m][q * 8];
                *(u32x4*)(adjF + (((size_t)(i0 >> 4) + it) * 256 + kt) * 512 + lane * 8) = v;
            }
        }
    }

#pragma unroll
    for (int mt = 0; mt < 4; ++mt)
#pragma unroll
        for (int r = 0; r < 4; ++r) {
            float v = dsum[mt][r];
            v += __shfl_xor(v, 1); v += __shfl_xor(v, 2);
            v += __shfl_xor(v, 4); v += __shfl_xor(v, 8);
            if (m == 0) atomicAdd(&d[i0 + mt * 16 + q * 4 + r], v);
        }
}

// ---------------- fc: fcF = frag-major bf16(rsqrt(d[i])*(cbnF @ WF + b)); also emits dinv ----------------
__global__ __launch_bounds__(256) void fc_kernel(const unsigned short* __restrict__ cbnF,
                                                 const unsigned short* __restrict__ WF,
                                                 const float* __restrict__ bias,
                                                 const float* __restrict__ dvec,
                                                 float* __restrict__ dinv,
                                                 unsigned short* __restrict__ fcF) {
    const int lane = threadIdx.x & 63;
    const int wave = threadIdx.x >> 6;
    const int m = lane & 15, q = lane >> 4;
    const int i0 = blockIdx.x * 64;
    const int ntg = blockIdx.y * 4 + wave;   // 0..31

    const u32x4* Ag = (const u32x4*)cbnF;
    const u32x4* Bg = (const u32x4*)WF;

    f32x4 acc[4] = {};
#pragma unroll
    for (int ct = 0; ct < 16; ++ct) {
        u32x4 bfr = Bg[((size_t)ntg * 16 + ct) * 64 + lane];
#pragma unroll
        for (int mt = 0; mt < 4; ++mt) {
            u32x4 afr = Ag[(((size_t)(i0 >> 4) + mt) * 16 + ct) * 64 + lane];
            acc[mt] = mfma16(afr, bfr, acc[mt]);
        }
    }
    float bv = bias[ntg * 16 + m];
#pragma unroll
    for (int mt = 0; mt < 4; ++mt) {
        int i = i0 + mt * 16 + q * 4;   // conv2 k-index (fc row)
        ushort4 o;
        o.x = f2bf((acc[mt][0] + bv) * rsqrtf(dvec[i + 0] + 1e-8f));
        o.y = f2bf((acc[mt][1] + bv) * rsqrtf(dvec[i + 1] + 1e-8f));
        o.z = f2bf((acc[mt][2] + bv) * rsqrtf(dvec[i + 2] + 1e-8f));
        o.w = f2bf((acc[mt][3] + bv) * rsqrtf(dvec[i + 3] + 1e-8f));
        size_t off = ((size_t)ntg * 256 + (i >> 5)) * 512
                   + (size_t)((i >> 3) & 3) * 128 + m * 8 + (q & 1) * 4;
        *(ushort4*)(fcF + off) = o;
    }
    // emit dinv for conv2's epilogue (fc launch completes before conv2 starts)
    if (blockIdx.y == 0 && threadIdx.x < 64)
        dinv[i0 + threadIdx.x] = rsqrtf(dvec[i0 + threadIdx.x] + 1e-8f);
}

// ---------------- conv2: out = sigmoid(dvi * (adj @ fc2)) — frag-major GEMM ----------------
// M=8192 N=512 K=8192. Block 128x128, 8 waves; wave = 16-col slice over 128 rows.
// K-chunk 128 dbuf LDS (64 KB), 1 barrier/chunk. ALL of chunk c+1's loads (A and B) issue
// at the TOP of chunk c, so the pre-barrier vmcnt(0) drain finds them ~1240 cyc old (free).
__global__ __launch_bounds__(512) void conv2_kernel(const unsigned short* __restrict__ adjF,
                                                    const unsigned short* __restrict__ fcF,
                                                    const float* __restrict__ dinv,
                                                    float* __restrict__ out) {
    const int bid = blockIdx.x;
    const int xcd = bid & 7;
    const int g = bid >> 3;               // 0..31
    const int iblk = (g >> 2) * 8 + xcd;  // A-slice cluster co-resident per XCD
    const int cblk = g & 3;
    const int i0 = iblk * 128;

    const int lane = threadIdx.x & 63;
    const int wave = threadIdx.x >> 6;    // 0..7
    const int m = lane & 15, q = lane >> 4;
    const int nt = cblk * 8 + wave;       // this wave's 16 output cols

    __shared__ __align__(16) unsigned short Abuf[2][4][8][512];  // 64 KB [buf][ktl][it][frag]

    const u32x4* Ag = (const u32x4*)adjF;
    const u32x4* Bg = (const u32x4*)fcF;
    const int itw = (i0 >> 4) + wave;     // wave stages it-tile = wave

    f32x4 acc[8] = {};
    u32x4 st[4], bq[2][4];

    // prologue: chunk 0
#pragma unroll
    for (int k = 0; k < 4; ++k)
        st[k] = Ag[((size_t)itw * 256 + k) * 64 + lane];
#pragma unroll
    for (int k = 0; k < 4; ++k)
        bq[0][k] = Bg[((size_t)nt * 256 + k) * 64 + lane];
#pragma unroll
    for (int k = 0; k < 4; ++k)
        *(u32x4*)&Abuf[0][k][wave][lane * 8] = st[k];
    __syncthreads();

#pragma unroll 2
    for (int c = 0; c < 64; ++c) {
        const int cur = c & 1, nxt = cur ^ 1;
        const int kb = c * 4;
        const int kbn = (c < 63) ? kb + 4 : kb;
        // issue ALL of chunk c+1's loads now (A then B): full MFMA phase covers latency
#pragma unroll
        for (int k = 0; k < 4; ++k)
            st[k] = Ag[((size_t)itw * 256 + kbn + k) * 64 + lane];
#pragma unroll
        for (int k = 0; k < 4; ++k)
            bq[nxt][k] = Bg[((size_t)nt * 256 + kbn + k) * 64 + lane];
        // consume current chunk
#pragma unroll
        for (int ktl = 0; ktl < 4; ++ktl) {
            u32x4 pa[8];
#pragma unroll
            for (int mt = 0; mt < 8; ++mt)
                pa[mt] = *(const u32x4*)&Abuf[cur][ktl][mt][lane * 8];
#pragma unroll
            for (int mt = 0; mt < 8; ++mt)
                acc[mt] = mfma16(pa[mt], bq[cur][ktl], acc[mt]);
        }
        // publish chunk c+1 (A regs ready: issued first, oldest in vmcnt queue)
#pragma unroll
        for (int k = 0; k < 4; ++k)
            *(u32x4*)&Abuf[nxt][k][wave][lane * 8] = st[k];
        __syncthreads();
    }

#pragma unroll
    for (int mt = 0; mt < 8; ++mt)
#pragma unroll
        for (int r = 0; r < 4; ++r) {
            int row = i0 + mt * 16 + q * 4 + r;
            float dv = dinv[row];
            float xv = acc[mt][r] * dv;
            out[(size_t)row * CDIM + cblk * 128 + wave * 16 + m] = 1.0f / (1.0f + __expf(-xv));
        }
}

extern "C" void kernel_launch(void* const* d_in, const int* in_sizes, int n_in,
                              void* d_out, int out_size, void* d_ws, size_t ws_size,
                              hipStream_t stream) {
    const float* bbn = (const float*)d_in[0];
    const float* cbn = (const float*)d_in[1];
    const float* W   = (const float*)d_in[2];
    const float* b   = (const float*)d_in[3];
    float* out = (float*)d_out;  // reference output is float32

    char* ws = (char*)d_ws;
    unsigned short* tbf  = (unsigned short*)(ws);                 // 1 MB
    float* s             = (float*)(ws + (1u << 20));             // 32 KB
    float* d             = (float*)(ws + (1u << 20) + 32768);     // 32 KB
    float* dinv          = (float*)(ws + (1u << 20) + 65536);     // 32 KB
    unsigned short* fcF  = (unsigned short*)(ws + (2u << 20));    // 8 MB
    unsigned short* cbnF = (unsigned short*)(ws + (10u << 20));   // 8 MB
    unsigned short* WF   = (unsigned short*)(ws + (18u << 20));   // 0.5 MB
    unsigned short* adjF = (unsigned short*)(ws + (19u << 20));   // 128 MiB

    prep_kernel<<<NN * 16 / 256, 256, 0, stream>>>(bbn, tbf, s);
    prep_cw_kernel<<<544, 256, 0, stream>>>(cbn, W, cbnF, WF);
    hipMemsetAsync(d, 0, NN * sizeof(float), stream);
    scoredeg_kernel<<<dim3(NN / 64, 16), 256, 0, stream>>>(tbf, s, d, adjF);
    fc_kernel<<<dim3(NN / 64, 8), 256, 0, stream>>>(cbnF, WF, b, d, dinv, fcF);
    conv2_kernel<<<256, 512, 0, stream>>>(adjF, fcF, dinv, out);
}